// Round 9
// baseline (210.144 us; speedup 1.0000x reference)
//
#include <hip/hip_runtime.h>

// All-pole time-varying IIR via chunked affine-state decomposition.
// y[t] = K[t]*x[t] - sum_m A[t][m]*y[t-1-m], coeffs lin-interp per 80-sample frame.
// C=100 chunks of L=160. phase1 builds per-chunk affine maps (M_c,f_c); phase2 scans
// them per batch; phase3 re-runs chunks exactly from known start states.
//
// phase1/phase3: pair-lane tap-split IIR core (even lane taps 0-14, odd lane taps
// 15-29 with reversed window; identical instruction stream, one shfl_xor per step).
//
// phase2 (round-8): LDS double-buffered scan. One block per batch; waves 1-3
// ISSUE next-segment global loads to regs BEFORE the scan and ds_write AFTER it
// (T14 split: HBM latency hides under wave 0's ~4000-cyc scan). Wave 0 scans
// 10 chunks/segment from LDS (conflict-free: lanes 0-29 -> distinct banks).
// r7 post-mortem: global-memory scan exposed ~2400 cyc/step (~100us) because the
// depth-4 reg prefetch was defeated by vmcnt tracking limits + branchy guards.
//
// Lessons: static local-array indices only (r2); launch_bounds must leave VGPR
// headroom, (256,6) collapsed to VGPR=40+spill (r6); column-contiguous Mf stores
// (r5); no scalar-broadcast LDS matmul reads, stage coalesced (r4).

#define Bb 64
#define Tt 16000
#define Nn 200
#define Pp 80
#define Mm 30
#define Cc 100
#define Ll 160
#define NBLK (Ll / 4)  // 40

#define MF_FLOATS ((size_t)Bb * Cc * 930)
#define SS_FLOATS ((size_t)Bb * Cc * 32)

__device__ __forceinline__ float bcast(float v, int l) {
  return __uint_as_float(__builtin_amdgcn_readlane(__float_as_uint(v), l));
}

// load this lane's 15-tap coefficient half (boff = 15 for even/recent, 30 for odd/old)
__device__ __forceinline__ void load_half(const float* __restrict__ p0,
                                          const float* __restrict__ p1, int boff,
                                          float (&cf)[15], float (&df)[15],
                                          float& K0, float& dK) {
  K0 = p0[0];
  dK = p1[0] - K0;
#pragma unroll
  for (int j = 0; j < 15; ++j) {
    float v0 = p0[boff - j];
    cf[j] = v0;
    df[j] = p1[boff - j] - v0;
  }
}

// ---------------- Phase 1: per-chunk transition matrices ----------------
// wave = one chunk; lanes 2r,2r+1 = role r (r=0..30: 30 unit-state cols + input run).
__global__ __launch_bounds__(256, 4) void phase1(const float* __restrict__ x,
                                                 const float* __restrict__ a,
                                                 float* __restrict__ Mf) {
  const int tid = threadIdx.x;
  const int wch = blockIdx.x * 4 + (tid >> 6);  // chunk id = b*Cc + c
  const int lane = tid & 63;
  const int role = lane >> 1;
  const int isB = lane & 1;  // 0 = recent taps, 1 = old taps
  const int b = wch / Cc, c = wch % Cc;
  const float gmask = (lane == 60) ? 1.f : 0.f;  // role 30, even lane: input-driven

  // window: even w[i]=y[t-15+i]; odd w[i]=y[t-30+i] (i=0..14 valid at block start)
  float w[19];
  const int sbase = isB ? 29 : 14;  // initial state e_role: w[i]=s[sbase-i]
#pragma unroll
  for (int i = 0; i < 19; ++i) w[i] = (i < 15 && (sbase - i) == role) ? 1.f : 0.f;

  const int n0 = 2 * c;
  const float* ar = a + ((size_t)b * Nn + n0) * 31;
  const int boff = isB ? 30 : 15;
  float cf[15], df[15], K0, dK;
  load_half(ar, ar + 31, boff, cf, df, K0, dK);

  const float* xp = x + (size_t)b * Tt + c * Ll;
  const float finc = 1.0f / Pp;
  float fbase = 0.f;

#pragma unroll 1
  for (int blk = 0; blk < NBLK; ++blk) {
    if (blk == NBLK / 2) {
      const float* p0 = ar + 31;
      const float* p1 = (n0 + 2 < Nn) ? p0 + 31 : p0;
      load_half(p0, p1, boff, cf, df, K0, dK);
      fbase = 0.f;
    }
    const float4 xq = *reinterpret_cast<const float4*>(xp + blk * 4);
    float recv[4];
#pragma unroll
    for (int k = 0; k < 4; ++k) recv[k] = __shfl_xor(w[k], 1, 64);
#pragma unroll
    for (int k = 0; k < 4; ++k) {
      float aa = 0.f, ab = 0.f, dd = 0.f, db = 0.f;
#pragma unroll
      for (int j = 0; j < 14; j += 2) {
        aa = fmaf(cf[j], w[j + k], aa);
        dd = fmaf(df[j], w[j + k], dd);
        ab = fmaf(cf[j + 1], w[j + 1 + k], ab);
        db = fmaf(df[j + 1], w[j + 1 + k], db);
      }
      aa = fmaf(cf[14], w[14 + k], aa);
      dd = fmaf(df[14], w[14 + k], dd);
      const float f = fmaf((float)k, finc, fbase);
      const float p = fmaf(f, dd + db, aa + ab);
      const float q = __shfl_xor(p, 1, 64);
      const float Kt = fmaf(dK, f, K0);
      const float xk = (k == 0) ? xq.x : (k == 1) ? xq.y : (k == 2) ? xq.z : xq.w;
      const float y = fmaf(gmask, Kt * xk, -(p + q));
      w[15 + k] = isB ? recv[k] : y;
    }
#pragma unroll
    for (int i = 0; i < 15; ++i) w[i] = w[i + 4];
    fbase += 4.0f * finc;
  }

  // store column `role`: rows 0-14 from even lane, 15-29 from odd; s_end[j]=w[14-j]
  if (role <= 30) {
    float* dst = Mf + (size_t)wch * 930 + role * 30 + (isB ? 15 : 0);
#pragma unroll
    for (int j = 0; j < 15; ++j) dst[j] = w[14 - j];
  }
}

// ---------------- Phase 2: LDS double-buffered per-batch scan ----------------
__device__ __forceinline__ void p2ld_lds(const float* base, int cis, int lane,
                                         float (&R)[31]) {
  const float* nb = base + cis * 930;
  if (lane < Mm) {
#pragma unroll
    for (int j = 0; j < 31; ++j) R[j] = nb[j * 30 + lane];  // ds_read, banks distinct
  }
}

__device__ __forceinline__ float p2st(float s, const float (&R)[31]) {
  float a0 = R[30], a1 = 0.f;
#pragma unroll
  for (int j = 0; j < Mm; j += 2) {
    a0 = fmaf(R[j], bcast(s, j), a0);
    a1 = fmaf(R[j + 1], bcast(s, j + 1), a1);
  }
  return a0 + a1;
}

template <int C>
__global__ __launch_bounds__(256, 1) void phase2(const float* __restrict__ Mf,
                                                 float* __restrict__ Sstart) {
  constexpr int SEG = 10;
  constexpr int NSEG = C / SEG;    // 10
  constexpr int SEGF = SEG * 930;  // 9300 floats per segment
  constexpr int SEG16 = SEGF / 4;  // 2325 float4s
  __shared__ float lds[2][SEGF];   // 74.4 KB

  const int b = blockIdx.x;
  const int tid = threadIdx.x;
  const int wave = tid >> 6;
  const int lane = tid & 63;
  const float* src = Mf + (size_t)b * C * 930;
  const int chb = b * C;

  // prologue: stage segment 0 with all 256 threads (latency exposed once)
  {
    float4 v[10];
#pragma unroll
    for (int u = 0; u < 10; ++u) {
      int i = tid + u * 256;
      if (i < SEG16) v[u] = *reinterpret_cast<const float4*>(src + (size_t)i * 4);
    }
#pragma unroll
    for (int u = 0; u < 10; ++u) {
      int i = tid + u * 256;
      if (i < SEG16) *reinterpret_cast<float4*>(&lds[0][i * 4]) = v[u];
    }
  }
  __syncthreads();

  float s = 0.f;
#pragma unroll 1
  for (int seg = 0; seg < NSEG; ++seg) {
    const int cur = seg & 1;
    const int t3 = tid - 64;
    float4 v[13];
    // waves 1-3: ISSUE next segment's loads (latency hides under wave 0's scan)
    if (seg + 1 < NSEG && wave > 0) {
      const float* s1 = src + (size_t)(seg + 1) * SEGF;
#pragma unroll
      for (int u = 0; u < 13; ++u) {
        int i = t3 + u * 192;
        if (i < SEG16) v[u] = *reinterpret_cast<const float4*>(s1 + (size_t)i * 4);
      }
    }
    // wave 0: scan SEG chunks out of LDS
    if (wave == 0) {
      const float* base = &lds[cur][0];
      float RA[31], RB[31];
      p2ld_lds(base, 0, lane, RA);
      for (int cis = 0; cis < SEG; cis += 2) {
        p2ld_lds(base, cis + 1, lane, RB);
        if (lane < Mm) Sstart[(size_t)(chb + seg * SEG + cis) * 32 + lane] = s;
        s = p2st(s, RA);
        if (cis + 2 < SEG) p2ld_lds(base, cis + 2, lane, RA);
        if (lane < Mm) Sstart[(size_t)(chb + seg * SEG + cis + 1) * 32 + lane] = s;
        s = p2st(s, RB);
      }
    }
    // waves 1-3: write staged segment (vmcnt wait lands here, post-scan)
    if (seg + 1 < NSEG && wave > 0) {
      float* dst = &lds[cur ^ 1][0];
#pragma unroll
      for (int u = 0; u < 13; ++u) {
        int i = t3 + u * 192;
        if (i < SEG16) *reinterpret_cast<float4*>(dst + (size_t)i * 4) = v[u];
      }
    }
    __syncthreads();
  }
}

// ---------------- Phase 3: exact re-run, lane-pair per chunk ----------------
__global__ __launch_bounds__(256, 4) void phase3(const float* __restrict__ x,
                                                 const float* __restrict__ a,
                                                 const float* __restrict__ Sstart,
                                                 float* __restrict__ out) {
  const int gtid = blockIdx.x * 256 + threadIdx.x;  // 50 blocks * 256 = 12800
  const int ch = gtid >> 1;
  const int isB = gtid & 1;
  const int b = ch / Cc, c = ch % Cc;
  const float gmask = isB ? 0.f : 1.f;

  const float* sp = Sstart + (size_t)ch * 32;
  const int sbase = isB ? 29 : 14;
  float w[19];
#pragma unroll
  for (int i = 0; i < 15; ++i) w[i] = sp[sbase - i];
#pragma unroll
  for (int i = 15; i < 19; ++i) w[i] = 0.f;

  const int n0 = 2 * c;
  const float* ar = a + ((size_t)b * Nn + n0) * 31;
  const int boff = isB ? 30 : 15;
  float cf[15], df[15], K0, dK;
  load_half(ar, ar + 31, boff, cf, df, K0, dK);

  const float* xp = x + (size_t)b * Tt + c * Ll;
  float* yp = out + (size_t)b * Tt + c * Ll;
  const float finc = 1.0f / Pp;
  float fbase = 0.f;

#pragma unroll 1
  for (int blk = 0; blk < NBLK; ++blk) {
    if (blk == NBLK / 2) {
      const float* p0 = ar + 31;
      const float* p1 = (n0 + 2 < Nn) ? p0 + 31 : p0;
      load_half(p0, p1, boff, cf, df, K0, dK);
      fbase = 0.f;
    }
    const float4 xq = *reinterpret_cast<const float4*>(xp + blk * 4);
    float recv[4];
#pragma unroll
    for (int k = 0; k < 4; ++k) recv[k] = __shfl_xor(w[k], 1, 64);
#pragma unroll
    for (int k = 0; k < 4; ++k) {
      float aa = 0.f, ab = 0.f, dd = 0.f, db = 0.f;
#pragma unroll
      for (int j = 0; j < 14; j += 2) {
        aa = fmaf(cf[j], w[j + k], aa);
        dd = fmaf(df[j], w[j + k], dd);
        ab = fmaf(cf[j + 1], w[j + 1 + k], ab);
        db = fmaf(df[j + 1], w[j + 1 + k], db);
      }
      aa = fmaf(cf[14], w[14 + k], aa);
      dd = fmaf(df[14], w[14 + k], dd);
      const float f = fmaf((float)k, finc, fbase);
      const float p = fmaf(f, dd + db, aa + ab);
      const float q = __shfl_xor(p, 1, 64);
      const float Kt = fmaf(dK, f, K0);
      const float xk = (k == 0) ? xq.x : (k == 1) ? xq.y : (k == 2) ? xq.z : xq.w;
      const float y = fmaf(gmask, Kt * xk, -(p + q));
      w[15 + k] = isB ? recv[k] : y;
    }
    if (!isB) {
      *reinterpret_cast<float4*>(yp + blk * 4) = make_float4(w[15], w[16], w[17], w[18]);
    }
#pragma unroll
    for (int i = 0; i < 15; ++i) w[i] = w[i + 4];
    fbase += 4.0f * finc;
  }
}

// ---------------- Naive fallback ----------------
__global__ void naive_kernel(const float* __restrict__ x, const float* __restrict__ a,
                             float* __restrict__ out) {
  const int b = blockIdx.x * blockDim.x + threadIdx.x;
  if (b >= Bb) return;
  float h[Mm];
#pragma unroll
  for (int m = 0; m < Mm; ++m) h[m] = 0.f;
  for (int n = 0; n < Nn; ++n) {
    const float* p0 = a + ((size_t)b * Nn + n) * 31;
    const float* p1 = a + ((size_t)b * Nn + min(n + 1, Nn - 1)) * 31;
    float c0[Mm], dc[Mm];
#pragma unroll
    for (int m = 0; m < Mm; ++m) {
      float v0 = p0[m + 1];
      c0[m] = v0;
      dc[m] = p1[m + 1] - v0;
    }
    const float K0 = p0[0], dK = p1[0] - K0;
    const float* xp = x + (size_t)b * Tt + n * Pp;
    float* yp = out + (size_t)b * Tt + n * Pp;
    for (int i = 0; i < Pp; ++i) {
      const float f = (float)i * (1.0f / Pp);
      float acc = 0.f;
#pragma unroll
      for (int m = 0; m < Mm; ++m) acc = fmaf(fmaf(dc[m], f, c0[m]), h[m], acc);
      const float y = fmaf(fmaf(dK, f, K0), xp[i], -acc);
      yp[i] = y;
#pragma unroll
      for (int m = Mm - 1; m > 0; --m) h[m] = h[m - 1];
      h[0] = y;
    }
  }
}

extern "C" void kernel_launch(void* const* d_in, const int* in_sizes, int n_in,
                              void* d_out, int out_size, void* d_ws, size_t ws_size,
                              hipStream_t stream) {
  const float* x = (const float*)d_in[0];  // (64,16000) f32
  const float* a = (const float*)d_in[1];  // (64,200,31) f32
  float* out = (float*)d_out;              // (64,16000) f32

  const size_t need = (MF_FLOATS + SS_FLOATS) * sizeof(float);
  if (ws_size < need) {
    naive_kernel<<<1, 64, 0, stream>>>(x, a, out);
    return;
  }
  float* Mf = (float*)d_ws;
  float* Sstart = Mf + MF_FLOATS;

  // 6400 chunk-waves, 4 per block
  phase1<<<Bb * Cc / 4, 256, 0, stream>>>(x, a, Mf);
  // one block per batch, LDS double-buffered scan
  phase2<Cc><<<Bb, 256, 0, stream>>>(Mf, Sstart);
  // 6400 chunks x 2 lanes = 12800 threads
  phase3<<<Bb * Cc * 2 / 256, 256, 0, stream>>>(x, a, Sstart, out);
}